// Round 8
// baseline (962.848 us; speedup 1.0000x reference)
//
#include <hip/hip_runtime.h>
#include <hip/hip_cooperative_groups.h>
#include <math.h>

namespace cg = cooperative_groups;

#define NB 8
#define SS 512
#define HH 768
#define NHD 12
#define HDIM 64
#define DWD 300
#define WW 256
#define LL 4
#define KC 6          // K-chunks for 768-deep matvecs (128 each)

struct Params {
    const float* x; const int* ids; const int* wi; const float* table;
    const float* lam; const float* mu;
    const float* dt_w; const float* dt_b; const float* dr_w; const float* dr_b;
    const float* q_w;  const float* q_b;  const float* k_w;  const float* k_b;
    const float* v_w;  const float* v_b;  const float* qi_w; const float* qi_b;
    const float* ki_w; const float* ki_b; const float* vi_w; const float* vi_b;
    const float* fus_w; const float* fus_b; const float* dense_w; const float* dense_b;
    const float* cls_w; const float* cls_b;
    float* out;
    float* xmix; float* tbuf; float* we; float* scores; float* r; float* cst;
    int* keep; float* cgb; float* qpart; float* q0g; float* part1; float* part2;
};

__device__ __forceinline__ float waveReduceSum(float v){
    #pragma unroll
    for(int o=32;o>0;o>>=1) v += __shfl_xor(v,o,64);
    return v;
}

// One cooperative kernel; 9 stages separated by grid.sync().
// Shared arena (15.5 KB) aliased per stage; 4 blocks/CU guaranteed by launch_bounds.
__global__ __launch_bounds__(256, 4) void mega(Params P){
    cg::grid_group gridg = cg::this_grid();
    const int bid = blockIdx.x;
    const int t   = threadIdx.x;
    const int NBLK = gridDim.x;
    __shared__ float sm[3872];

    // ================= S1: embed GEMM1 + keep-zero + q-partials (544 units)
    for(int wb=bid; wb<544; wb+=NBLK){
        if(wb >= 400){                 // q0/qi0 partials
            int rb = wb - 400;
            int kc = rb % KC;
            int jt = (rb/KC) % 3;
            int b  = rb / (KC*3);
            int j = jt*256 + t;
            const float* x0 = P.x + (size_t)b*SS*HH;   // seq pos 0 (never inside a word)
            int i0 = kc*128;
            float a1=0.f, a2=0.f;
            for(int i=i0;i<i0+128;i++){
                float xv = x0[i];
                a1 += xv*P.q_w[(size_t)i*HH+j];
                a2 += xv*P.qi_w[(size_t)i*HH+j];
            }
            P.qpart[(((size_t)kc*NB + b)*2 + 0)*HH + j] = a1;
            P.qpart[(((size_t)kc*NB + b)*2 + 1)*HH + j] = a2;
        } else if(wb >= 384){          // keep-zero
            int i = (wb-384)*256 + t;
            if(i < NB*SS) P.keep[i] = 0;
        } else {                       // GEMM1: tanh(table[ids]@dt_w + dt_b) 2048x300x768
            const int K=300, NT=19;
            float (*As)[68] = (float(*)[68])sm;
            float (*Bs)[68] = (float(*)[68])(sm+1088);
            int bx = wb % 12, by = wb / 12;
            int m0 = by*64, n0 = bx*64;
            int tm = t>>4, tn = t&15;
            int lm = t>>2, lk = (t&3)*4;
            int kk = t>>4, c4 = (t&15)*4;
            int row_id = P.ids[m0+lm];
            const float* arow = P.table + (size_t)row_id*DWD;
            float acc[4][4] = {};
            float4 av, bv;
            if(lk < K) av = *(const float4*)&arow[lk]; else av = make_float4(0,0,0,0);
            if(kk < K) bv = *(const float4*)&P.dt_w[(size_t)kk*HH + n0 + c4]; else bv = make_float4(0,0,0,0);
            for(int kt=0;kt<NT;kt++){
                __syncthreads();
                As[lk+0][lm]=av.x; As[lk+1][lm]=av.y; As[lk+2][lm]=av.z; As[lk+3][lm]=av.w;
                *(float4*)&Bs[kk][c4] = bv;
                __syncthreads();
                if(kt+1 < NT){
                    int k0 = (kt+1)*16;
                    if(k0+lk < K) av = *(const float4*)&arow[k0+lk]; else av = make_float4(0,0,0,0);
                    if(k0+kk < K) bv = *(const float4*)&P.dt_w[(size_t)(k0+kk)*HH + n0 + c4]; else bv = make_float4(0,0,0,0);
                }
                #pragma unroll
                for(int k=0;k<16;k++){
                    float4 a = *(const float4*)&As[k][tm*4];
                    float4 b = *(const float4*)&Bs[k][tn*4];
                    acc[0][0]+=a.x*b.x; acc[0][1]+=a.x*b.y; acc[0][2]+=a.x*b.z; acc[0][3]+=a.x*b.w;
                    acc[1][0]+=a.y*b.x; acc[1][1]+=a.y*b.y; acc[1][2]+=a.y*b.z; acc[1][3]+=a.y*b.w;
                    acc[2][0]+=a.z*b.x; acc[2][1]+=a.z*b.y; acc[2][2]+=a.z*b.z; acc[2][3]+=a.z*b.w;
                    acc[3][0]+=a.w*b.x; acc[3][1]+=a.w*b.y; acc[3][2]+=a.w*b.z; acc[3][3]+=a.w*b.w;
                }
            }
            #pragma unroll
            for(int i=0;i<4;i++){
                int m = m0 + tm*4 + i;
                int n = n0 + tn*4;
                float4 o;
                o.x = tanhf(acc[i][0] + P.dt_b[n+0]);
                o.y = tanhf(acc[i][1] + P.dt_b[n+1]);
                o.z = tanhf(acc[i][2] + P.dt_b[n+2]);
                o.w = tanhf(acc[i][3] + P.dt_b[n+3]);
                *(float4*)&P.tbuf[(size_t)m*HH + n] = o;
            }
        }
        __syncthreads();
    }
    gridg.sync();

    // ================= S2: embed GEMM2 + x->xmix copy + qred (3464 units)
    for(int wb=bid; wb<3464; wb+=NBLK){
        if(wb >= 3456){                // qred
            int b = wb - 3456;
            float* q0s  = sm;
            float* qi0s = sm + 768;
            for(int j=t;j<HH;j+=256){
                float a1=P.q_b[j], a2=P.qi_b[j];
                #pragma unroll
                for(int kc=0;kc<KC;kc++){
                    a1 += P.qpart[(((size_t)kc*NB+b)*2+0)*HH+j];
                    a2 += P.qpart[(((size_t)kc*NB+b)*2+1)*HH+j];
                }
                q0s[j]=a1; qi0s[j]=a2;
                P.q0g[((size_t)b*2+0)*HH+j]=a1;
                P.q0g[((size_t)b*2+1)*HH+j]=a2;
            }
            __syncthreads();
            if(t<24){
                int slot=t, h=slot%NHD;
                const float* Kb = (slot<NHD)? P.k_b : P.ki_b;
                const float* Q  = (slot<NHD)? q0s : qi0s;
                float a=0.f;
                for(int j=0;j<HDIM;j++) a += Kb[h*HDIM+j]*Q[h*HDIM+j];
                P.cst[b*24+slot]=a;
            }
        } else if(wb >= 384){          // copy x -> xmix (3072 units exact cover)
            int i = (wb-384)*256 + t;
            ((float4*)P.xmix)[i] = ((const float4*)P.x)[i];
        } else {                       // GEMM2: we = tbuf @ dr_w + dr_b  2048x768x768
            const int NT = 48;
            float (*As)[68] = (float(*)[68])sm;
            float (*Bs)[68] = (float(*)[68])(sm+1088);
            int bx = wb % 12, by = wb / 12;
            int m0 = by*64, n0 = bx*64;
            int tm = t>>4, tn = t&15;
            int lm = t>>2, lk = (t&3)*4;
            int kk = t>>4, c4 = (t&15)*4;
            const float* arow = P.tbuf + (size_t)(m0+lm)*HH;
            float acc[4][4] = {};
            float4 av = *(const float4*)&arow[lk];
            float4 bv = *(const float4*)&P.dr_w[(size_t)kk*HH + n0 + c4];
            for(int kt=0;kt<NT;kt++){
                __syncthreads();
                As[lk+0][lm]=av.x; As[lk+1][lm]=av.y; As[lk+2][lm]=av.z; As[lk+3][lm]=av.w;
                *(float4*)&Bs[kk][c4] = bv;
                __syncthreads();
                if(kt+1 < NT){
                    int k0 = (kt+1)*16;
                    av = *(const float4*)&arow[k0+lk];
                    bv = *(const float4*)&P.dr_w[(size_t)(k0+kk)*HH + n0 + c4];
                }
                #pragma unroll
                for(int k=0;k<16;k++){
                    float4 a = *(const float4*)&As[k][tm*4];
                    float4 b = *(const float4*)&Bs[k][tn*4];
                    acc[0][0]+=a.x*b.x; acc[0][1]+=a.x*b.y; acc[0][2]+=a.x*b.z; acc[0][3]+=a.x*b.w;
                    acc[1][0]+=a.y*b.x; acc[1][1]+=a.y*b.y; acc[1][2]+=a.y*b.z; acc[1][3]+=a.y*b.w;
                    acc[2][0]+=a.z*b.x; acc[2][1]+=a.z*b.y; acc[2][2]+=a.z*b.z; acc[2][3]+=a.z*b.w;
                    acc[3][0]+=a.w*b.x; acc[3][1]+=a.w*b.y; acc[3][2]+=a.w*b.z; acc[3][3]+=a.w*b.w;
                }
            }
            #pragma unroll
            for(int i=0;i<4;i++){
                int m = m0 + tm*4 + i;
                int n = n0 + tn*4;
                float4 o;
                o.x = acc[i][0] + P.dr_b[n+0];
                o.y = acc[i][1] + P.dr_b[n+1];
                o.z = acc[i][2] + P.dr_b[n+2];
                o.w = acc[i][3] + P.dr_b[n+3];
                *(float4*)&P.we[(size_t)m*HH + n] = o;
            }
        }
        __syncthreads();
    }
    gridg.sync();

    // ================= S3: per-word cos/softmax/mic/keep/mix + r-vectors (2624 units)
    for(int wb=bid; wb<2624; wb+=NBLK){
        if(wb >= 2048){                // r rider
            int rb = wb - 2048;
            int ct = rb % 3;
            int slot = (rb/3) % 24;
            int b = rb / 72;
            int h = slot % NHD;
            float* qs = sm;
            const float* Q = P.q0g + ((size_t)b*2 + (slot<NHD?0:1))*HH + h*HDIM;
            if(t<HDIM) qs[t] = Q[t];
            __syncthreads();
            const float* Kp = (slot<NHD)? P.k_w : P.ki_w;
            int c = ct*256 + t;
            const float4* K4 = (const float4*)(Kp + (size_t)c*HH + h*HDIM);
            const float4* q4 = (const float4*)qs;
            float a=0.f;
            #pragma unroll
            for(int j=0;j<16;j++){
                float4 kv=K4[j], qv=q4[j];
                a += kv.x*qv.x + kv.y*qv.y + kv.z*qv.z + kv.w*qv.w;
            }
            P.r[((size_t)(b*24+slot))*HH + c] = a;
        } else {                       // per-word block
            int bw = wb;
            int b = bw >> 8;
            int start = P.wi[bw*2+0];
            int end   = P.wi[bw*2+1];
            int n = end - start;
            if(n > 0){
                float* weS = sm;                 // 768
                float (*xrow)[HH] = (float(*)[HH])(sm+768);  // 4x768
                float* cos_s = sm + 3840;        // 4
                int wv = t>>6, lane = t&63;
                const float* wer = P.we + (size_t)bw*HH;
                float wev[12];
                float wn = 0.f;
                #pragma unroll
                for(int i=0;i<12;i++){
                    float v = wer[lane+64*i];
                    wev[i]=v; wn += v*v;
                    if(wv==0) weS[lane+64*i] = v;
                }
                wn = waveReduceSum(wn);
                if(wv < n){
                    const float* xr = P.x + ((size_t)(b*SS + start + wv))*HH;
                    float d=0.f, xs=0.f;
                    #pragma unroll
                    for(int i=0;i<12;i++){
                        float xv = xr[lane+64*i];
                        xrow[wv][lane+64*i] = xv;
                        d += xv*wev[i]; xs += xv*xv;
                    }
                    d = waveReduceSum(d); xs = waveReduceSum(xs);
                    if(lane==0) cos_s[wv] = d / sqrtf(xs*wn);
                } else {
                    if(lane==0) cos_s[wv] = -1e9f;
                }
                __syncthreads();
                float c0=cos_s[0], c1=cos_s[1], c2=cos_s[2], c3=cos_s[3];
                float m = fmaxf(fmaxf(c0,c1),fmaxf(c2,c3));
                float e0 = (0<n)? expf(c0-m):0.f;
                float e1 = (1<n)? expf(c1-m):0.f;
                float e2 = (2<n)? expf(c2-m):0.f;
                float e3 = (3<n)? expf(c3-m):0.f;
                float inv = 1.f/(e0+e1+e2+e3);
                float s0=e0*inv, s1=e1*inv, s2=e2*inv, s3=e3*inv;
                int mic = 0; float bv = c0;
                if(c1 > bv){bv=c1;mic=1;}
                if(c2 > bv){bv=c2;mic=2;}
                if(c3 > bv){bv=c3;mic=3;}
                if(t==0) P.keep[b*SS + start + mic] = 1;
                float f = expf(P.lam[0] - 1.f);
                float a = (n>1)? (1.f-f)/(float)(n-1) : (1.f-f);
                for(int j=t; j<HH; j+=256){
                    float wej = weS[j];
                    float v0=0.f,v1=0.f,v2=0.f,v3=0.f;
                    if(0<n) v0 = xrow[0][j] + s0*wej;
                    if(1<n) v1 = xrow[1][j] + s1*wej;
                    if(2<n) v2 = xrow[2][j] + s2*wej;
                    if(3<n) v3 = xrow[3][j] + s3*wej;
                    float sumx = v0+v1+v2+v3;
                    float xm = (mic==0)?v0:(mic==1)?v1:(mic==2)?v2:v3;
                    float mm = f*xm + a*(sumx-xm);
                    if(0<n) P.xmix[((size_t)(b*SS+start+0))*HH+j] = (0==mic)? (n==1? v0 : mm) : ((1.f-a)*v0 + a*xm);
                    if(1<n) P.xmix[((size_t)(b*SS+start+1))*HH+j] = (1==mic)? mm : ((1.f-a)*v1 + a*xm);
                    if(2<n) P.xmix[((size_t)(b*SS+start+2))*HH+j] = (2==mic)? mm : ((1.f-a)*v2 + a*xm);
                    if(3<n) P.xmix[((size_t)(b*SS+start+3))*HH+j] = (3==mic)? mm : ((1.f-a)*v3 + a*xm);
                }
            }
        }
        __syncthreads();
    }
    gridg.sync();

    // ================= S4: scores (4096 units)
    for(int wb=bid; wb<NB*SS; wb+=NBLK){
        int b = wb >> 9, s = wb & 511;
        float* xr = sm;
        for(int i=t;i<HH;i+=256) xr[i] = P.xmix[(size_t)wb*HH + i];
        __syncthreads();
        int wv = t>>6, lane = t&63;
        int kp = P.keep[b*SS + s];
        #pragma unroll
        for(int q=0;q<6;q++){
            int slot = wv*6 + q;
            const float* rr = P.r + ((size_t)(b*24+slot))*HH;
            float d = 0.f;
            #pragma unroll
            for(int i=0;i<12;i++) d += xr[lane+64*i]*rr[lane+64*i];
            d = waveReduceSum(d);
            if(lane==0){
                float sc = (d + P.cst[b*24+slot])*0.125f;
                if(slot>=12 && !kp) sc = -1e30f;
                P.scores[((size_t)(b*24+slot))*SS + s] = sc;
            }
        }
        __syncthreads();
    }
    gridg.sync();

    // ================= S5: softmax + weighted row-sum -> cg (576 units)
    for(int wb=bid; wb<NB*24*3; wb+=NBLK){
        int jt = wb % 3;
        int bslot = wb / 3;
        int b = bslot / 24;
        float* p   = sm;        // 512
        float* red = sm + 512;  // 256
        const float* srow = P.scores + (size_t)bslot*SS;
        float v0 = srow[t], v1 = srow[t+256];
        red[t] = fmaxf(v0,v1); __syncthreads();
        for(int o=128;o>0;o>>=1){ if(t<o) red[t] = fmaxf(red[t],red[t+o]); __syncthreads(); }
        float m = red[0]; __syncthreads();
        float e0 = expf(v0-m), e1 = expf(v1-m);
        red[t] = e0+e1; __syncthreads();
        for(int o=128;o>0;o>>=1){ if(t<o) red[t] += red[t+o]; __syncthreads(); }
        float inv = 1.f/red[0];
        p[t] = e0*inv; p[t+256] = e1*inv;
        __syncthreads();
        int j = jt*256 + t;
        const float* xb = P.xmix + (size_t)b*SS*HH + j;
        float a0 = 0.f;
        for(int s=0;s<SS;s++) a0 += p[s]*xb[(size_t)s*HH];
        P.cgb[((size_t)bslot)*HH + j] = a0;
        __syncthreads();
    }
    gridg.sync();

    // ================= S6: finA partials (144 units)
    for(int wb=bid; wb<NB*3*KC; wb+=NBLK){
        int kc = wb % KC;
        int jt = (wb/KC) % 3;
        int b  = wb / (KC*3);
        int j = jt*256 + t;
        int h = j >> 6;
        float mu = P.mu[0];
        const float* c1 = P.cgb + ((size_t)(b*24+h))*HH;
        const float* c2 = P.cgb + ((size_t)(b*24+12+h))*HH;
        int i0 = kc*128;
        float a1=0.f, a2=0.f;
        for(int i=i0;i<i0+128;i++){
            a1 += c1[i]*P.v_w[(size_t)i*HH+j];
            a2 += c2[i]*P.vi_w[(size_t)i*HH+j];
        }
        P.part1[((size_t)kc*NB+b)*HH + j] = mu*a1 + (1.f-mu)*a2;
    }
    gridg.sync();

    // ================= S7: finB (144 units)
    for(int wb=bid; wb<NB*3*KC; wb+=NBLK){
        int kc = wb % KC;
        int jt = (wb/KC) % 3;
        int b  = wb / (KC*3);
        int i0 = kc*128;
        float* gs = sm;
        if(t < 128){
            int i = i0 + t;
            float mu = P.mu[0];
            float s = mu*P.v_b[i] + (1.f-mu)*P.vi_b[i];
            #pragma unroll
            for(int k2=0;k2<KC;k2++) s += P.part1[((size_t)k2*NB+b)*HH + i];
            gs[t] = s;
        }
        __syncthreads();
        int j = jt*256 + t;
        float a = 0.f;
        for(int k=0;k<128;k++) a += gs[k]*P.fus_w[(size_t)(i0+k)*HH + j];
        P.part2[((size_t)kc*NB+b)*HH + j] = a;
        __syncthreads();
    }
    gridg.sync();

    // ================= S8: finC (144 units)
    for(int wb=bid; wb<NB*3*KC; wb+=NBLK){
        int kc = wb % KC;
        int jt = (wb/KC) % 3;
        int b  = wb / (KC*3);
        int i0 = kc*128;
        float* fs = sm;
        if(t < 128){
            int i = i0 + t;
            float s = P.fus_b[i];
            #pragma unroll
            for(int k2=0;k2<KC;k2++) s += P.part2[((size_t)k2*NB+b)*HH + i];
            fs[t] = tanhf(s);
        }
        __syncthreads();
        int j = jt*256 + t;
        float a = 0.f;
        for(int k=0;k<128;k++) a += fs[k]*P.dense_w[(size_t)(i0+k)*HH + j];
        P.part1[((size_t)kc*NB+b)*HH + j] = a;
        __syncthreads();
    }
    gridg.sync();

    // ================= S9: finD (8 units)
    for(int wb=bid; wb<NB; wb+=NBLK){
        int b = wb;
        float* pooled = sm;        // 768
        float* red    = sm + 768;  // 256
        for(int j=t;j<HH;j+=256){
            float s = P.dense_b[j];
            #pragma unroll
            for(int kc=0;kc<KC;kc++) s += P.part1[((size_t)kc*NB+b)*HH+j];
            pooled[j] = tanhf(s);
        }
        __syncthreads();
        float p0=0.f, p1=0.f;
        for(int i=t;i<HH;i+=256){ p0 += pooled[i]*P.cls_w[i*2+0]; p1 += pooled[i]*P.cls_w[i*2+1]; }
        red[t]=p0; __syncthreads();
        for(int o=128;o>0;o>>=1){ if(t<o) red[t]+=red[t+o]; __syncthreads(); }
        if(t==0) P.out[b*2+0] = red[0]+P.cls_b[0];
        __syncthreads();
        red[t]=p1; __syncthreads();
        for(int o=128;o>0;o>>=1){ if(t<o) red[t]+=red[t+o]; __syncthreads(); }
        if(t==0) P.out[b*2+1] = red[0]+P.cls_b[1];
        __syncthreads();
    }
}

extern "C" void kernel_launch(void* const* d_in, const int* in_sizes, int n_in,
                              void* d_out, int out_size, void* d_ws, size_t ws_size,
                              hipStream_t stream) {
    char* w = (char*)d_ws;
    Params hp;
    hp.x       = (const float*)d_in[0];
    hp.ids     = (const int*)  d_in[1];
    hp.wi      = (const int*)  d_in[2];
    hp.table   = (const float*)d_in[3];
    hp.lam     = (const float*)d_in[4];
    hp.mu      = (const float*)d_in[5];
    hp.dt_w = (const float*)d_in[6];   hp.dt_b = (const float*)d_in[7];
    hp.dr_w = (const float*)d_in[8];   hp.dr_b = (const float*)d_in[9];
    hp.q_w  = (const float*)d_in[10];  hp.q_b  = (const float*)d_in[11];
    hp.k_w  = (const float*)d_in[12];  hp.k_b  = (const float*)d_in[13];
    hp.v_w  = (const float*)d_in[14];  hp.v_b  = (const float*)d_in[15];
    hp.qi_w = (const float*)d_in[16];  hp.qi_b = (const float*)d_in[17];
    hp.ki_w = (const float*)d_in[18];  hp.ki_b = (const float*)d_in[19];
    hp.vi_w = (const float*)d_in[20];  hp.vi_b = (const float*)d_in[21];
    hp.fus_w = (const float*)d_in[22]; hp.fus_b = (const float*)d_in[23];
    hp.dense_w = (const float*)d_in[24]; hp.dense_b = (const float*)d_in[25];
    hp.cls_w = (const float*)d_in[26]; hp.cls_b = (const float*)d_in[27];
    hp.out = (float*)d_out;
    hp.xmix   = (float*)(w + 0);          // 12,582,912
    hp.tbuf   = (float*)(w + 12582912);   //  6,291,456
    hp.we     = (float*)(w + 18874368);   //  6,291,456
    hp.scores = (float*)(w + 25165824);   //    393,216
    hp.r      = (float*)(w + 25559040);   //    589,824
    hp.cst    = (float*)(w + 26148864);   //      1,024
    hp.keep   = (int*)  (w + 26149888);   //     16,384
    hp.cgb    = (float*)(w + 26166272);   //    589,824
    hp.qpart  = (float*)(w + 26756096);   //    294,912
    hp.q0g    = (float*)(w + 27051008);   //     49,152
    hp.part1  = (float*)(w + 27100160);   //    147,456
    hp.part2  = (float*)(w + 27247616);   //    147,456  -> total 27,395,072
    (void)ws_size; (void)in_sizes; (void)n_in; (void)out_size;

    int nb = 0;
    hipOccupancyMaxActiveBlocksPerMultiprocessor(&nb, mega, 256, 0);
    if(nb < 1) nb = 1;
    int gridn = nb * 256;                 // 256 CUs on MI355X
    if(gridn > 1024) gridn = 1024;        // grid-stride loops handle any grid
    void* args[] = { &hp };
    hipLaunchCooperativeKernel((void*)mega, dim3(gridn), dim3(256), args, 0, stream);
}

// Round 10
// 412.235 us; speedup vs baseline: 2.3357x; 2.3357x over previous
//
#include <hip/hip_runtime.h>
#include <math.h>

#define NB 8
#define SS 512
#define HH 768
#define NHD 12
#define HDIM 64
#define DWD 300
#define WW 256
#define LL 4
#define KC 6          // K-chunks for 768-deep matvecs (128 each)
#define SC 8          // s-chunks for attention weighted sum (64 each)

__device__ __forceinline__ float waveReduceSum(float v){
    #pragma unroll
    for(int o=32;o>0;o>>=1) v += __shfl_xor(v,o,64);
    return v;
}
__device__ __forceinline__ float waveReduceMax(float v){
    #pragma unroll
    for(int o=32;o>0;o>>=1) v = fmaxf(v, __shfl_xor(v,o,64));
    return v;
}

// ==== Kernel 1: GEMM1 (384 blocks) + keep-zero (16) + k_q partials (144) ====
// grid 544.  GEMM1: t = tanh(table[ids] @ dt_w + dt_b)  (2048x300x768), reg-dbuf.
__global__ __launch_bounds__(256) void k_embed1f(const float* __restrict__ table,
        const int* __restrict__ ids, const float* __restrict__ Wm,
        const float* __restrict__ bias, float* __restrict__ out,
        int* __restrict__ keep,
        const float* __restrict__ x, const float* __restrict__ qw,
        const float* __restrict__ qiw, float* __restrict__ qpart){
    int bid = blockIdx.x;
    int t = threadIdx.x;
    if(bid >= 400){                 // ---- k_q rider: q0/qi0 partials
        int rb = bid - 400;         // 0..143
        int kc = rb % KC;
        int jt = (rb/KC) % 3;
        int b  = rb / (KC*3);
        int j = jt*256 + t;
        const float* x0 = x + (size_t)b*SS*HH;   // seq position 0 (never inside a word)
        int i0 = kc*128;
        float a1=0.f, a2=0.f;
        for(int i=i0;i<i0+128;i++){
            float xv = x0[i];
            a1 += xv*qw[(size_t)i*HH+j];
            a2 += xv*qiw[(size_t)i*HH+j];
        }
        qpart[(((size_t)kc*NB + b)*2 + 0)*HH + j] = a1;
        qpart[(((size_t)kc*NB + b)*2 + 1)*HH + j] = a2;
        return;
    }
    if(bid >= 384){                 // ---- keep-zero rider
        int i = (bid-384)*256 + t;
        if(i < NB*SS) keep[i] = 0;
        return;
    }
    const int K=300, NT=19;         // ceil(300/16)
    __shared__ float As[16][68];
    __shared__ float Bs[16][68];
    int bx = bid % 12;              // N tile
    int by = bid / 12;              // M tile
    int m0 = by*64, n0 = bx*64;
    int tm = t>>4, tn = t&15;
    int lm = t>>2, lk = (t&3)*4;    // A: row lm, k lk..lk+3
    int kk = t>>4, c4 = (t&15)*4;   // B: k-row kk, cols c4..c4+3
    int row_id = ids[m0+lm];
    const float* arow = table + (size_t)row_id*DWD;
    float acc[4][4] = {};
    float4 av, bv;
    if(lk < K) av = *(const float4*)&arow[lk]; else av = make_float4(0,0,0,0);
    if(kk < K) bv = *(const float4*)&Wm[(size_t)kk*HH + n0 + c4]; else bv = make_float4(0,0,0,0);
    for(int kt=0;kt<NT;kt++){
        __syncthreads();
        As[lk+0][lm]=av.x; As[lk+1][lm]=av.y; As[lk+2][lm]=av.z; As[lk+3][lm]=av.w;
        *(float4*)&Bs[kk][c4] = bv;
        __syncthreads();
        if(kt+1 < NT){
            int k0 = (kt+1)*16;
            if(k0+lk < K) av = *(const float4*)&arow[k0+lk]; else av = make_float4(0,0,0,0);
            if(k0+kk < K) bv = *(const float4*)&Wm[(size_t)(k0+kk)*HH + n0 + c4]; else bv = make_float4(0,0,0,0);
        }
        #pragma unroll
        for(int k=0;k<16;k++){
            float4 a = *(const float4*)&As[k][tm*4];
            float4 b = *(const float4*)&Bs[k][tn*4];
            acc[0][0]+=a.x*b.x; acc[0][1]+=a.x*b.y; acc[0][2]+=a.x*b.z; acc[0][3]+=a.x*b.w;
            acc[1][0]+=a.y*b.x; acc[1][1]+=a.y*b.y; acc[1][2]+=a.y*b.z; acc[1][3]+=a.y*b.w;
            acc[2][0]+=a.z*b.x; acc[2][1]+=a.z*b.y; acc[2][2]+=a.z*b.z; acc[2][3]+=a.z*b.w;
            acc[3][0]+=a.w*b.x; acc[3][1]+=a.w*b.y; acc[3][2]+=a.w*b.z; acc[3][3]+=a.w*b.w;
        }
    }
    #pragma unroll
    for(int i=0;i<4;i++){
        int m = m0 + tm*4 + i;
        int n = n0 + tn*4;
        float4 o;
        o.x = tanhf(acc[i][0] + bias[n+0]);
        o.y = tanhf(acc[i][1] + bias[n+1]);
        o.z = tanhf(acc[i][2] + bias[n+2]);
        o.w = tanhf(acc[i][3] + bias[n+3]);
        *(float4*)&out[(size_t)m*HH + n] = o;
    }
}

// ==== Kernel 2: GEMM2 (384) + x->xmix copy (3072) + qred (8) ====
// grid 3464.  GEMM2: we = t @ dr_w + dr_b  (2048x768x768), reg-dbuf.
__global__ __launch_bounds__(256) void k_embed2f(const float* __restrict__ A,
        const float* __restrict__ Wm, const float* __restrict__ bias,
        float* __restrict__ out,
        const float4* __restrict__ xin4, float4* __restrict__ xmix4,
        const float* __restrict__ qpart,
        const float* __restrict__ qb, const float* __restrict__ qib,
        const float* __restrict__ kb, const float* __restrict__ kib,
        float* __restrict__ q0g, float* __restrict__ cst){
    int bid = blockIdx.x;
    int t = threadIdx.x;
    if(bid >= 3456){                // ---- qred rider (8 blocks)
        int b = bid - 3456;
        __shared__ float q0s[HH], qi0s[HH];
        for(int j=t;j<HH;j+=256){
            float a1=qb[j], a2=qib[j];
            #pragma unroll
            for(int kc=0;kc<KC;kc++){
                a1 += qpart[(((size_t)kc*NB+b)*2+0)*HH+j];
                a2 += qpart[(((size_t)kc*NB+b)*2+1)*HH+j];
            }
            q0s[j]=a1; qi0s[j]=a2;
            q0g[((size_t)b*2+0)*HH+j]=a1;
            q0g[((size_t)b*2+1)*HH+j]=a2;
        }
        __syncthreads();
        if(t<24){
            int slot=t, h=slot%NHD;
            const float* Kb = (slot<NHD)? kb:kib;
            const float* Q  = (slot<NHD)? q0s:qi0s;
            float a=0.f;
            for(int j=0;j<HDIM;j++) a += Kb[h*HDIM+j]*Q[h*HDIM+j];
            cst[b*24+slot]=a;
        }
        return;
    }
    if(bid >= 384){                 // ---- copy rider (3072 blocks, exact cover)
        int i = (bid-384)*256 + t;
        xmix4[i] = xin4[i];
        return;
    }
    const int NT = 48;              // 768/16
    __shared__ float As[16][68];
    __shared__ float Bs[16][68];
    int bx = bid % 12;
    int by = bid / 12;
    int m0 = by*64, n0 = bx*64;
    int tm = t>>4, tn = t&15;
    int lm = t>>2, lk = (t&3)*4;
    int kk = t>>4, c4 = (t&15)*4;
    const float* arow = A + (size_t)(m0+lm)*HH;
    float acc[4][4] = {};
    float4 av = *(const float4*)&arow[lk];
    float4 bv = *(const float4*)&Wm[(size_t)kk*HH + n0 + c4];
    for(int kt=0;kt<NT;kt++){
        __syncthreads();
        As[lk+0][lm]=av.x; As[lk+1][lm]=av.y; As[lk+2][lm]=av.z; As[lk+3][lm]=av.w;
        *(float4*)&Bs[kk][c4] = bv;
        __syncthreads();
        if(kt+1 < NT){
            int k0 = (kt+1)*16;
            av = *(const float4*)&arow[k0+lk];
            bv = *(const float4*)&Wm[(size_t)(k0+kk)*HH + n0 + c4];
        }
        #pragma unroll
        for(int k=0;k<16;k++){
            float4 a = *(const float4*)&As[k][tm*4];
            float4 b = *(const float4*)&Bs[k][tn*4];
            acc[0][0]+=a.x*b.x; acc[0][1]+=a.x*b.y; acc[0][2]+=a.x*b.z; acc[0][3]+=a.x*b.w;
            acc[1][0]+=a.y*b.x; acc[1][1]+=a.y*b.y; acc[1][2]+=a.y*b.z; acc[1][3]+=a.y*b.w;
            acc[2][0]+=a.z*b.x; acc[2][1]+=a.z*b.y; acc[2][2]+=a.z*b.z; acc[2][3]+=a.z*b.w;
            acc[3][0]+=a.w*b.x; acc[3][1]+=a.w*b.y; acc[3][2]+=a.w*b.z; acc[3][3]+=a.w*b.w;
        }
    }
    #pragma unroll
    for(int i=0;i<4;i++){
        int m = m0 + tm*4 + i;
        int n = n0 + tn*4;
        float4 o;
        o.x = acc[i][0] + bias[n+0];
        o.y = acc[i][1] + bias[n+1];
        o.z = acc[i][2] + bias[n+2];
        o.w = acc[i][3] + bias[n+3];
        *(float4*)&out[(size_t)m*HH + n] = o;
    }
}

// ==== Kernel 3: per-word cos+softmax+mic+keep+mix (2048) + k_r (576) ====
// grid 2624
__global__ __launch_bounds__(256) void k_cosmix(const float* __restrict__ x,
        const int* __restrict__ wi, const float* __restrict__ we,
        const float* __restrict__ lam, int* __restrict__ keep,
        float* __restrict__ xmix,
        const float* __restrict__ q0g, const float* __restrict__ kw,
        const float* __restrict__ kiw, float* __restrict__ r){
    int bid = blockIdx.x;
    int t = threadIdx.x;
    if(bid >= 2048){                // ---- k_r rider (576 blocks)
        int rb = bid - 2048;
        int ct = rb % 3;
        int slot = (rb/3) % 24;
        int b = rb / 72;
        int h = slot % NHD;
        __shared__ float qs[HDIM];
        const float* Q = q0g + ((size_t)b*2 + (slot<NHD?0:1))*HH + h*HDIM;
        if(t<HDIM) qs[t] = Q[t];
        __syncthreads();
        const float* K = (slot<NHD)? kw : kiw;
        int c = ct*256 + t;
        const float4* K4 = (const float4*)(K + (size_t)c*HH + h*HDIM);
        const float4* q4 = (const float4*)qs;
        float a=0.f;
        #pragma unroll
        for(int j=0;j<16;j++){
            float4 kv=K4[j], qv=q4[j];
            a += kv.x*qv.x + kv.y*qv.y + kv.z*qv.z + kv.w*qv.w;
        }
        r[((size_t)(b*24+slot))*HH + c] = a;
        return;
    }
    // ---- per-word block: wave l handles row start+l
    int bw = bid;
    int b = bw >> 8;                // /WW
    int start = wi[bw*2+0];
    int end   = wi[bw*2+1];
    int n = end - start;
    if(n <= 0) return;
    __shared__ float weS[HH];
    __shared__ float xrow[LL][HH];
    __shared__ float cos_s[LL];
    int wv = t>>6, lane = t&63;
    const float* wer = we + (size_t)bw*HH;
    float wev[12];
    float wn = 0.f;
    #pragma unroll
    for(int i=0;i<12;i++){
        float v = wer[lane+64*i];
        wev[i]=v; wn += v*v;
        if(wv==0) weS[lane+64*i] = v;
    }
    wn = waveReduceSum(wn);
    if(wv < n){
        const float* xr = x + ((size_t)(b*SS + start + wv))*HH;
        float d=0.f, xs=0.f;
        #pragma unroll
        for(int i=0;i<12;i++){
            float xv = xr[lane+64*i];
            xrow[wv][lane+64*i] = xv;
            d += xv*wev[i]; xs += xv*xv;
        }
        d = waveReduceSum(d); xs = waveReduceSum(xs);
        if(lane==0) cos_s[wv] = d / sqrtf(xs*wn);
    } else {
        if(lane==0) cos_s[wv] = -1e9f;
    }
    __syncthreads();
    float c0=cos_s[0], c1=cos_s[1], c2=cos_s[2], c3=cos_s[3];
    float m = fmaxf(fmaxf(c0,c1),fmaxf(c2,c3));
    float e0 = (0<n)? expf(c0-m):0.f;
    float e1 = (1<n)? expf(c1-m):0.f;
    float e2 = (2<n)? expf(c2-m):0.f;
    float e3 = (3<n)? expf(c3-m):0.f;
    float inv = 1.f/(e0+e1+e2+e3);
    float s0=e0*inv, s1=e1*inv, s2=e2*inv, s3=e3*inv;
    int mic = 0; float bv = c0;
    if(c1 > bv){bv=c1;mic=1;}
    if(c2 > bv){bv=c2;mic=2;}
    if(c3 > bv){bv=c3;mic=3;}
    if(t==0) keep[b*SS + start + mic] = 1;
    float f = expf(lam[0] - 1.f);
    float a = (n>1)? (1.f-f)/(float)(n-1) : (1.f-f);
    for(int j=t; j<HH; j+=256){
        float wej = weS[j];
        float v0=0.f,v1=0.f,v2=0.f,v3=0.f;
        if(0<n) v0 = xrow[0][j] + s0*wej;
        if(1<n) v1 = xrow[1][j] + s1*wej;
        if(2<n) v2 = xrow[2][j] + s2*wej;
        if(3<n) v3 = xrow[3][j] + s3*wej;
        float sumx = v0+v1+v2+v3;
        float xm = (mic==0)?v0:(mic==1)?v1:(mic==2)?v2:v3;
        float mm = f*xm + a*(sumx-xm);   // mix_mic
        if(0<n) xmix[((size_t)(b*SS+start+0))*HH+j] = (0==mic)? (n==1? v0 : mm) : ((1.f-a)*v0 + a*xm);
        if(1<n) xmix[((size_t)(b*SS+start+1))*HH+j] = (1==mic)? mm : ((1.f-a)*v1 + a*xm);
        if(2<n) xmix[((size_t)(b*SS+start+2))*HH+j] = (2==mic)? mm : ((1.f-a)*v2 + a*xm);
        if(3<n) xmix[((size_t)(b*SS+start+3))*HH+j] = (3==mic)? mm : ((1.f-a)*v3 + a*xm);
    }
}

// ==== Kernel 4: scores[b,slot,s] = (x_mix[b,s]·r + cst)/8, keep-mask slots>=12 ====
__global__ __launch_bounds__(256) void k_scores(const float* __restrict__ xmix,
        const float* __restrict__ r, const float* __restrict__ cst,
        const int* __restrict__ keep, float* __restrict__ scores){
    int bs = blockIdx.x;
    int b = bs >> 9, s = bs & 511;
    __shared__ float xr[HH];
    for(int i=threadIdx.x;i<HH;i+=256) xr[i] = xmix[(size_t)bs*HH + i];
    __syncthreads();
    int wv = threadIdx.x>>6, lane = threadIdx.x&63;
    int kp = keep[b*SS + s];
    #pragma unroll
    for(int q=0;q<6;q++){
        int slot = wv*6 + q;
        const float* rr = r + ((size_t)(b*24+slot))*HH;
        float d = 0.f;
        #pragma unroll
        for(int i=0;i<12;i++) d += xr[lane+64*i]*rr[lane+64*i];
        d = waveReduceSum(d);
        if(lane==0){
            float sc = (d + cst[b*24+slot])*0.125f;
            if(slot>=12 && !kp) sc = -1e30f;
            scores[((size_t)(b*24+slot))*SS + s] = sc;
        }
    }
}

// ==== Kernel 5: softmax(redundant stats) + chunk weighted row-sum partials ====
// grid 8b*3jt*8sc = 192.  Reads xmix ONCE total (vs 24x in old k_attn).
__global__ __launch_bounds__(256) void k_smc(const float* __restrict__ scores,
        const float* __restrict__ xmix, float* __restrict__ cgp){
    int bid = blockIdx.x;
    int sc = bid & 7;
    int jt = (bid>>3) % 3;
    int b  = bid / 24;
    int t = threadIdx.x;
    int wv = t>>6, lane = t&63;
    __shared__ float mstat[24], istat[24];
    __shared__ float pchunk[24][64];
    // stats: wave wv handles slots 6wv..6wv+5 (each lane reads 8 of 512)
    #pragma unroll
    for(int q=0;q<6;q++){
        int slot = wv*6 + q;
        const float* srow = scores + ((size_t)(b*24+slot))*SS;
        float mv = -3.4e38f;
        #pragma unroll
        for(int i=0;i<8;i++) mv = fmaxf(mv, srow[lane+64*i]);
        mv = waveReduceMax(mv);
        float sv = 0.f;
        #pragma unroll
        for(int i=0;i<8;i++) sv += expf(srow[lane+64*i] - mv);
        sv = waveReduceSum(sv);
        if(lane==0){ mstat[slot] = mv; istat[slot] = 1.f/sv; }
    }
    __syncthreads();
    // pchunk[slot][ss] for this s-chunk
    int s0 = sc*64;
    for(int idx=t; idx<24*64; idx+=256){
        int slot = idx>>6, ss = idx&63;
        pchunk[slot][ss] = expf(scores[((size_t)(b*24+slot))*SS + s0+ss] - mstat[slot]) * istat[slot];
    }
    __syncthreads();
    // accumulate: thread owns column j; 24 slot-accumulators in regs
    int j = jt*256 + t;
    const float* xb = xmix + (size_t)b*SS*HH + j;
    float acc[24];
    #pragma unroll
    for(int sl=0;sl<24;sl++) acc[sl] = 0.f;
    for(int ss=0;ss<64;ss++){
        float xv = xb[(size_t)(s0+ss)*HH];
        #pragma unroll
        for(int sl=0;sl<24;sl++) acc[sl] += pchunk[sl][ss]*xv;
    }
    #pragma unroll
    for(int sl=0;sl<24;sl++)
        cgp[(((size_t)sc*NB + b)*24 + sl)*HH + j] = acc[sl];
}

// ==== Kernel 6: finA — reduce cgp chunks (LDS) + mu*h1+(1-mu)*h2 partials (144) ====
__global__ __launch_bounds__(256) void k_finA(const float* __restrict__ cgp,
        const float* __restrict__ vw, const float* __restrict__ viw,
        const float* __restrict__ mu_, float* __restrict__ part){
    int kc = blockIdx.x % KC;
    int jt = (blockIdx.x/KC) % 3;
    int b  = blockIdx.x / (KC*3);
    int t = threadIdx.x;
    int i0 = kc*128;
    // pre-reduce the 8 rows needed by this block: slots jt*4..jt*4+3 and +12, i in [i0,i0+128)
    __shared__ float red[8][128];
    for(int idx=t; idx<8*128; idx+=256){
        int row = idx>>7, ii = idx&127;
        int slot = (row<4)? (jt*4+row) : (jt*4+row-4+12);
        float s = 0.f;
        #pragma unroll
        for(int sc2=0;sc2<SC;sc2++)
            s += cgp[(((size_t)sc2*NB + b)*24 + slot)*HH + i0 + ii];
        red[row][ii] = s;
    }
    __syncthreads();
    int j = jt*256 + t;
    int hh = (j>>6) - jt*4;               // 0..3, wave-uniform
    float mu = mu_[0];
    float a1=0.f, a2=0.f;
    for(int k=0;k<128;k++){
        int i = i0 + k;
        a1 += red[hh][k]  * vw[(size_t)i*HH+j];
        a2 += red[hh+4][k]* viw[(size_t)i*HH+j];
    }
    part[((size_t)kc*NB+b)*HH + j] = mu*a1 + (1.f-mu)*a2;
}

// ==== Kernel 7: fused g-slice reduce + fus_w matvec  (144 blocks) ====
__global__ __launch_bounds__(256) void k_finB(const float* __restrict__ part1,
        const float* __restrict__ vb, const float* __restrict__ vib,
        const float* __restrict__ mu_, const float* __restrict__ fw,
        float* __restrict__ part2){
    int kc = blockIdx.x % KC;
    int jt = (blockIdx.x/KC) % 3;
    int b  = blockIdx.x / (KC*3);
    int i0 = kc*128;
    int t = threadIdx.x;
    __shared__ float gs[128];
    if(t < 128){
        int i = i0 + t;
        float mu = mu_[0];
        float s = mu*vb[i] + (1.f-mu)*vib[i];
        #pragma unroll
        for(int k2=0;k2<KC;k2++) s += part1[((size_t)k2*NB+b)*HH + i];
        gs[t] = s;
    }
    __syncthreads();
    int j = jt*256 + t;
    float a = 0.f;
    for(int k=0;k<128;k++) a += gs[k]*fw[(size_t)(i0+k)*HH + j];
    part2[((size_t)kc*NB+b)*HH + j] = a;
}

// ==== Kernel 8: fused fus-slice (tanh) + dense_w matvec  (144 blocks) ====
__global__ __launch_bounds__(256) void k_finC(const float* __restrict__ part2,
        const float* __restrict__ fb, const float* __restrict__ dw,
        float* __restrict__ part1){
    int kc = blockIdx.x % KC;
    int jt = (blockIdx.x/KC) % 3;
    int b  = blockIdx.x / (KC*3);
    int i0 = kc*128;
    int t = threadIdx.x;
    __shared__ float fs[128];
    if(t < 128){
        int i = i0 + t;
        float s = fb[i];
        #pragma unroll
        for(int k2=0;k2<KC;k2++) s += part2[((size_t)k2*NB+b)*HH + i];
        fs[t] = tanhf(s);
    }
    __syncthreads();
    int j = jt*256 + t;
    float a = 0.f;
    for(int k=0;k<128;k++) a += fs[k]*dw[(size_t)(i0+k)*HH + j];
    part1[((size_t)kc*NB+b)*HH + j] = a;
}

// ==== Kernel 9: pooled = tanh(sum + db); logits  (8 blocks) ====
__global__ __launch_bounds__(256) void k_finD(const float* __restrict__ part,
        const float* __restrict__ db, const float* __restrict__ cw,
        const float* __restrict__ cb, float* __restrict__ out){
    int b = blockIdx.x;
    int t = threadIdx.x;
    __shared__ float pooled[HH];
    __shared__ float red[256];
    for(int j=t;j<HH;j+=256){
        float s = db[j];
        #pragma unroll
        for(int kc=0;kc<KC;kc++) s += part[((size_t)kc*NB+b)*HH+j];
        pooled[j] = tanhf(s);
    }
    __syncthreads();
    float p0=0.f, p1=0.f;
    for(int i=t;i<HH;i+=256){ p0 += pooled[i]*cw[i*2+0]; p1 += pooled[i]*cw[i*2+1]; }
    red[t]=p0; __syncthreads();
    for(int o=128;o>0;o>>=1){ if(t<o) red[t]+=red[t+o]; __syncthreads(); }
    if(t==0) out[b*2+0] = red[0]+cb[0];
    __syncthreads();
    red[t]=p1; __syncthreads();
    for(int o=128;o>0;o>>=1){ if(t<o) red[t]+=red[t+o]; __syncthreads(); }
    if(t==0) out[b*2+1] = red[0]+cb[1];
}

extern "C" void kernel_launch(void* const* d_in, const int* in_sizes, int n_in,
                              void* d_out, int out_size, void* d_ws, size_t ws_size,
                              hipStream_t stream) {
    const float* x          = (const float*)d_in[0];
    const int*   word_ids   = (const int*)  d_in[1];
    const int*   word_index = (const int*)  d_in[2];
    const float* table      = (const float*)d_in[3];
    const float* lam        = (const float*)d_in[4];
    const float* mu         = (const float*)d_in[5];
    const float* dt_w = (const float*)d_in[6];
    const float* dt_b = (const float*)d_in[7];
    const float* dr_w = (const float*)d_in[8];
    const float* dr_b = (const float*)d_in[9];
    const float* q_w  = (const float*)d_in[10];
    const float* q_b  = (const float*)d_in[11];
    const float* k_w  = (const float*)d_in[12];
    const float* k_b  = (const float*)d_in[13];
    const float* v_w  = (const float*)d_in[14];
    const float* v_b  = (const float*)d_in[15];
    const float* qi_w = (const float*)d_in[16];
    const float* qi_b = (const float*)d_in[17];
    const float* ki_w = (const float*)d_in[18];
    const float* ki_b = (const float*)d_in[19];
    const float* vi_w = (const float*)d_in[20];
    const float* vi_b = (const float*)d_in[21];
    const float* fus_w = (const float*)d_in[22];
    const float* fus_b = (const float*)d_in[23];
    const float* dense_w = (const float*)d_in[24];
    const float* dense_b = (const float*)d_in[25];
    const float* cls_w = (const float*)d_in[26];
    const float* cls_b = (const float*)d_in[27];
    float* out = (float*)d_out;

    char* w = (char*)d_ws;
    float* xmix   = (float*)(w + 0);          // 12,582,912
    float* tbuf   = (float*)(w + 12582912);   //  6,291,456
    float* we     = (float*)(w + 18874368);   //  6,291,456
    float* scores = (float*)(w + 25165824);   //    393,216
    float* r      = (float*)(w + 25559040);   //    589,824
    float* cst    = (float*)(w + 26148864);   //      1,024
    int*   keep   = (int*)  (w + 26149888);   //     16,384
    float* qpart  = (float*)(w + 26756096);   //    294,912
    float* q0g    = (float*)(w + 27051008);   //     49,152
    float* part1  = (float*)(w + 27100160);   //    147,456
    float* part2  = (float*)(w + 27247616);   //    147,456
    float* cgp    = (float*)(w + 27395072);   //  4,718,592  -> total 32,113,664
    (void)ws_size; (void)in_sizes; (void)n_in; (void)out_size;

    // 1: embed GEMM1 (dbuf) + keep-zero + q-partials
    k_embed1f<<<544, 256, 0, stream>>>(table, word_ids, dt_w, dt_b, tbuf, keep,
                                       x, q_w, qi_w, qpart);
    // 2: embed GEMM2 (dbuf) + x->xmix copy + q-reduce/cst
    k_embed2f<<<3464, 256, 0, stream>>>(tbuf, dr_w, dr_b, we,
                                        (const float4*)x, (float4*)xmix,
                                        qpart, q_b, qi_b, k_b, ki_b, q0g, cst);
    // 3: per-word cos/softmax/mic/keep/mix + r-vectors
    k_cosmix<<<2624, 256, 0, stream>>>(x, word_index, we, lam, keep, xmix,
                                       q0g, k_w, ki_w, r);
    // 4: rank-1 attention scores
    k_scores<<<NB*SS, 256, 0, stream>>>(xmix, r, cst, keep, scores);
    // 5: softmax stats (redundant) + chunked weighted row-sum -> cgp
    k_smc<<<NB*3*SC, 256, 0, stream>>>(scores, xmix, cgp);
    // 6-9: epilogue (K-chunked matvecs, fused slice-reduces)
    k_finA<<<NB*3*KC, 256, 0, stream>>>(cgp, v_w, vi_w, mu, part1);
    k_finB<<<NB*3*KC, 256, 0, stream>>>(part1, v_b, vi_b, mu, fus_w, part2);
    k_finC<<<NB*3*KC, 256, 0, stream>>>(part2, fus_b, dense_w, part1);
    k_finD<<<NB, 256, 0, stream>>>(part1, dense_b, cls_w, cls_b, out);
}